// Round 8
// baseline (129.199 us; speedup 1.0000x reference)
//
#include <hip/hip_runtime.h>

#define F 32  // F_IN == F_OUT == 32

typedef __attribute__((ext_vector_type(8))) unsigned short us8;
typedef __attribute__((ext_vector_type(4))) float f4;
typedef __attribute__((ext_vector_type(2))) int i2;

// ---- bf16 helpers (manual RNE) ----
static __device__ __forceinline__ unsigned short f2bf(float f) {
    unsigned int u = __float_as_uint(f);
    u += 0x7FFF + ((u >> 16) & 1);
    return (unsigned short)(u >> 16);
}
static __device__ __forceinline__ float bf2f(unsigned short s) {
    return __uint_as_float(((unsigned int)s) << 16);
}

// Fused prologue. Blocks [0, nxw): y = x @ W^T in bf16, 64 nodes/block.
// Blocks [nxw, ...): CSR row-ptr boundary scatter + (col,val) int2 packing.
__global__ __launch_bounds__(256) void prologue_kernel(
    const float* __restrict__ x, const float* __restrict__ W,
    const int* __restrict__ rows,
    const int* __restrict__ cols, const float* __restrict__ vals,
    unsigned short* __restrict__ y, int* __restrict__ ptr,
    i2* __restrict__ packed,
    int N, int E, int nxw) {
    int b = blockIdx.x;
    int t = threadIdx.x;
    if (b < nxw) {
        __shared__ float Wt[F * F];        // Wt[fi*32+fo]
        __shared__ float xs[64 * F];       // 64 node rows
        #pragma unroll
        for (int k = 0; k < 4; ++k) {
            int i = t + k * 256;
            Wt[(i & 31) * F + (i >> 5)] = W[i];
        }
        int n0 = b * 64;
        const f4* __restrict__ x4 = (const f4*)(x + (size_t)n0 * F);
        f4* __restrict__ xs4 = (f4*)xs;
        int limit4 = (N * F - n0 * F) >> 2;
        #pragma unroll
        for (int k = 0; k < 2; ++k) {
            int i = t + k * 256;
            f4 z = {0.f, 0.f, 0.f, 0.f};
            xs4[i] = (i < limit4) ? x4[i] : z;
        }
        __syncthreads();
        int fo = t & 31;
        int j0 = (t >> 5) * 8;
        #pragma unroll
        for (int j = 0; j < 8; ++j) {
            int nl = j0 + j;
            float acc = 0.0f;
            #pragma unroll
            for (int fi = 0; fi < F; ++fi)
                acc = fmaf(xs[nl * F + fi], Wt[fi * F + fo], acc);
            int n = n0 + nl;
            if (n < N) y[(size_t)n * F + fo] = f2bf(acc);
        }
    } else {
        int e = (b - nxw) * 256 + t;
        if (e <= E) {
            int prev = (e == 0) ? -1 : rows[e - 1];
            int cur  = (e == E) ? N  : rows[e];
            for (int r = prev + 1; r <= cur; ++r) ptr[r] = e;
        }
        if (e < E) {
            i2 p;
            p.x = cols[e];
            p.y = __float_as_int(vals[e]);
            packed[e] = p;
        }
    }
}

// Hot kernel: wave = 16 groups x 4 lanes; each group owns TWO consecutive
// nodes and walks their FUSED contiguous edge range [s0, s2) (split s1) in
// 8-edge chunks. Contributions routed to the right node by masking val
// (va = e<s1 ? v : 0; vb = complementary) -> two fma chains, no divergent
// per-node loops (trip = ceil(sum-deg/8), ~25% fewer iters than max-of-two).
// Edge stream = packed int2 NT loads (1 instr/edge, no L2 pollution);
// y row gathers stay cached. Zero LDS, zero shuffles.
__global__ __launch_bounds__(256) void gnn_kernel(
    const unsigned short* __restrict__ y,
    const i2*  __restrict__ packed,
    const int* __restrict__ row_ptr,
    const float* __restrict__ bias,
    float*       __restrict__ out, int N) {
    int t = threadIdx.x;
    int lane = t & 63;
    int g = lane >> 2;           // group 0..15 (owns 2 nodes)
    int l = lane & 3;            // feature slice: 8l..8l+7
    int base = (blockIdx.x * 4 + (t >> 6)) * 32;
    int na = base + 2 * g;
    int ia = na     < N ? na     : N;
    int ib = na + 1 < N ? na + 1 : N;
    int ic = na + 2 < N ? na + 2 : N;
    int s0 = row_ptr[ia];
    int s1 = row_ptr[ib];
    int s2 = row_ptr[ic];

    const us8* __restrict__ y8 = (const us8*)y;   // 4 x ushort8 per row

    float a0[8], a1[8];
    #pragma unroll
    for (int i = 0; i < 8; ++i) { a0[i] = 0.f; a1[i] = 0.f; }

    for (int e = s0; e < s2; e += 8) {
        int ee[8];
        #pragma unroll
        for (int k = 0; k < 8; ++k) {
            int ek = e + k;
            ee[k] = (ek < s2) ? ek : (s2 - 1);     // clamp: always in-range
        }
        i2 p[8];
        #pragma unroll
        for (int k = 0; k < 8; ++k)
            p[k] = __builtin_nontemporal_load(&packed[ee[k]]);
        float va[8], vb[8];
        #pragma unroll
        for (int k = 0; k < 8; ++k) {
            float v = __int_as_float(p[k].y);
            int ek = e + k;
            va[k] = (ek < s1) ? v : 0.f;                 // node A share
            vb[k] = (ek >= s1 && ek < s2) ? v : 0.f;     // node B share
        }
        us8 r[8];
        #pragma unroll
        for (int k = 0; k < 8; ++k)
            r[k] = y8[(p[k].x << 2) + l];
        #pragma unroll
        for (int k = 0; k < 8; ++k) {
            #pragma unroll
            for (int i = 0; i < 8; ++i) {
                float xf = bf2f(r[k][i]);
                a0[i] = fmaf(xf, va[k], a0[i]);
                a1[i] = fmaf(xf, vb[k], a1[i]);
            }
        }
    }

    const float* __restrict__ bp = bias + l * 8;
    if (na < N) {
        f4 o0, o1;
        o0.x = fmaxf(a0[0] + bp[0], 0.f);
        o0.y = fmaxf(a0[1] + bp[1], 0.f);
        o0.z = fmaxf(a0[2] + bp[2], 0.f);
        o0.w = fmaxf(a0[3] + bp[3], 0.f);
        o1.x = fmaxf(a0[4] + bp[4], 0.f);
        o1.y = fmaxf(a0[5] + bp[5], 0.f);
        o1.z = fmaxf(a0[6] + bp[6], 0.f);
        o1.w = fmaxf(a0[7] + bp[7], 0.f);
        f4* op = (f4*)(out + (size_t)na * F + l * 8);
        __builtin_nontemporal_store(o0, op);
        __builtin_nontemporal_store(o1, op + 1);
    }
    if (na + 1 < N) {
        f4 o0, o1;
        o0.x = fmaxf(a1[0] + bp[0], 0.f);
        o0.y = fmaxf(a1[1] + bp[1], 0.f);
        o0.z = fmaxf(a1[2] + bp[2], 0.f);
        o0.w = fmaxf(a1[3] + bp[3], 0.f);
        o1.x = fmaxf(a1[4] + bp[4], 0.f);
        o1.y = fmaxf(a1[5] + bp[5], 0.f);
        o1.z = fmaxf(a1[6] + bp[6], 0.f);
        o1.w = fmaxf(a1[7] + bp[7], 0.f);
        f4* op = (f4*)(out + (size_t)(na + 1) * F + l * 8);
        __builtin_nontemporal_store(o0, op);
        __builtin_nontemporal_store(o1, op + 1);
    }
}

// ---- Fallback (ws too small): round-2 proven fp32 kernel ----
__global__ __launch_bounds__(256) void gnn_fp32_kernel(
    const float* __restrict__ x,
    const int*   __restrict__ rows,
    const int*   __restrict__ cols,
    const float* __restrict__ vals,
    const float* __restrict__ W,
    const float* __restrict__ bias,
    float*       __restrict__ out,
    int N, int E) {
    __shared__ float Wt[F * F];
    __shared__ float bS[F];
    int t = threadIdx.x;
    for (int i = t; i < F * F; i += 256)
        Wt[(i & 31) * F + (i >> 5)] = W[i];
    if (t < F) bS[t] = bias[t];
    __syncthreads();
    int lane = t & 63;
    int n = blockIdx.x * 4 + (t >> 6);
    if (n >= N) return;
    int g = lane >> 3, l = lane & 7;
    int target = n + (lane >> 5);
    int lo = 0, hi = E;
    while (lo < hi) { int mid = (lo + hi) >> 1; if (rows[mid] < target) lo = mid + 1; else hi = mid; }
    int start = __shfl(lo, 0), end = __shfl(lo, 32);
    const float4* __restrict__ x4 = (const float4*)x;
    float4 acc0 = {0,0,0,0}, acc1 = {0,0,0,0};
    for (int e0 = start; e0 < end; e0 += 16) {
        int ea = e0 + g, eb = ea + 8;
        if (ea < end) { int c = cols[ea]; float v = vals[ea]; float4 xr = x4[c * 8 + l];
            acc0.x = fmaf(xr.x, v, acc0.x); acc0.y = fmaf(xr.y, v, acc0.y);
            acc0.z = fmaf(xr.z, v, acc0.z); acc0.w = fmaf(xr.w, v, acc0.w); }
        if (eb < end) { int c = cols[eb]; float v = vals[eb]; float4 xr = x4[c * 8 + l];
            acc1.x = fmaf(xr.x, v, acc1.x); acc1.y = fmaf(xr.y, v, acc1.y);
            acc1.z = fmaf(xr.z, v, acc1.z); acc1.w = fmaf(xr.w, v, acc1.w); }
    }
    acc0.x += acc1.x; acc0.y += acc1.y; acc0.z += acc1.z; acc0.w += acc1.w;
    #pragma unroll
    for (int m = 8; m < 64; m <<= 1) {
        acc0.x += __shfl_xor(acc0.x, m); acc0.y += __shfl_xor(acc0.y, m);
        acc0.z += __shfl_xor(acc0.z, m); acc0.w += __shfl_xor(acc0.w, m);
    }
    float comp[4] = {acc0.x, acc0.y, acc0.z, acc0.w};
    int fo = lane & 31;
    float o = bS[fo];
    #pragma unroll
    for (int fi = 0; fi < F; ++fi)
        o = fmaf(__shfl(comp[fi & 3], fi >> 2), Wt[fi * F + fo], o);
    if (lane < F) out[n * F + fo] = fmaxf(o, 0.0f);
}

extern "C" void kernel_launch(void* const* d_in, const int* in_sizes, int n_in,
                              void* d_out, int out_size, void* d_ws, size_t ws_size,
                              hipStream_t stream) {
    const float* x    = (const float*)d_in[0];
    const int*   rows = (const int*)  d_in[1];
    const int*   cols = (const int*)  d_in[2];
    const float* vals = (const float*)d_in[3];
    const float* W    = (const float*)d_in[4];
    const float* bias = (const float*)d_in[5];
    float*       out  = (float*)d_out;

    int N = in_sizes[0] / F;
    int E = in_sizes[1];

    size_t rp_bytes = (size_t)(N + 1) * sizeof(int);
    size_t pk_off   = (rp_bytes + 255) & ~(size_t)255;
    size_t y_off    = (pk_off + (size_t)E * 8 + 255) & ~(size_t)255;
    size_t need     = y_off + (size_t)N * F * sizeof(unsigned short);

    if (ws_size >= need) {
        int* row_ptr = (int*)d_ws;
        i2*  packed  = (i2*)((char*)d_ws + pk_off);
        unsigned short* y = (unsigned short*)((char*)d_ws + y_off);
        int nxw  = (N + 63) / 64;
        int ncsr = (E + 1 + 255) / 256;
        prologue_kernel<<<nxw + ncsr, 256, 0, stream>>>(
            x, W, rows, cols, vals, y, row_ptr, packed, N, E, nxw);
        gnn_kernel<<<(N + 127) / 128, 256, 0, stream>>>(
            y, packed, row_ptr, bias, out, N);
    } else {
        gnn_fp32_kernel<<<(N + 3) / 4, 256, 0, stream>>>(
            x, rows, cols, vals, W, bias, out, N, E);
    }
}

// Round 9
// 113.581 us; speedup vs baseline: 1.1375x; 1.1375x over previous
//
#include <hip/hip_runtime.h>

#define F 32  // F_IN == F_OUT == 32

typedef __attribute__((ext_vector_type(8))) unsigned short us8;
typedef __attribute__((ext_vector_type(4))) float f4;

// ---- f16 helpers (header-free; default cast = RNE) ----
static __device__ __forceinline__ unsigned short f2h(float f) {
    _Float16 h = (_Float16)f;
    return __builtin_bit_cast(unsigned short, h);
}
static __device__ __forceinline__ float h2f(unsigned short s) {
    return (float)__builtin_bit_cast(_Float16, s);
}

// Fused prologue. Blocks [0, nxw): y = x @ W^T in f16, 64 nodes/block.
// Blocks [nxw, ...): CSR row-ptr boundary scatter from sorted rows.
__global__ __launch_bounds__(256) void prologue_kernel(
    const float* __restrict__ x, const float* __restrict__ W,
    const int* __restrict__ rows,
    unsigned short* __restrict__ y, int* __restrict__ ptr,
    int N, int E, int nxw) {
    int b = blockIdx.x;
    int t = threadIdx.x;
    if (b < nxw) {
        __shared__ float Wt[F * F];        // Wt[fi*32+fo]
        __shared__ float xs[64 * F];       // 64 node rows
        #pragma unroll
        for (int k = 0; k < 4; ++k) {
            int i = t + k * 256;
            Wt[(i & 31) * F + (i >> 5)] = W[i];
        }
        int n0 = b * 64;
        const f4* __restrict__ x4 = (const f4*)(x + (size_t)n0 * F);
        f4* __restrict__ xs4 = (f4*)xs;
        int limit4 = (N * F - n0 * F) >> 2;
        #pragma unroll
        for (int k = 0; k < 2; ++k) {
            int i = t + k * 256;
            f4 z = {0.f, 0.f, 0.f, 0.f};
            xs4[i] = (i < limit4) ? x4[i] : z;
        }
        __syncthreads();
        int fo = t & 31;
        int j0 = (t >> 5) * 8;
        #pragma unroll
        for (int j = 0; j < 8; ++j) {
            int nl = j0 + j;
            float acc = 0.0f;
            #pragma unroll
            for (int fi = 0; fi < F; ++fi)
                acc = fmaf(xs[nl * F + fi], Wt[fi * F + fo], acc);
            int n = n0 + nl;
            if (n < N) y[(size_t)n * F + fo] = f2h(acc);
        }
    } else {
        int e = (b - nxw) * 256 + t;
        if (e > E) return;
        int prev = (e == 0) ? -1 : rows[e - 1];
        int cur  = (e == E) ? N  : rows[e];
        for (int r = prev + 1; r <= cur; ++r) ptr[r] = e;
    }
}

// Hot kernel (round-6 structure): wave = 16 nodes x 4 lanes. Lane l of group
// g loads ushort8 (16B = features 8l..8l+7 of a 64B f16 row). 8-edge unroll
// with clamped predication -> ~10 gathers in flight per wave; 2 accumulator
// chains. Plain loads (L2/L1 reuse of edge stream), NT only on final store.
// Inner accumulate: fmaf((float)f16, f32, f32) -> v_fma_mix_f32 (no separate
// cvt), halving per-edge VALU vs the bf16 lshl+fma sequence.
__global__ __launch_bounds__(256) void gnn_kernel(
    const unsigned short* __restrict__ y,
    const int*   __restrict__ cols,
    const float* __restrict__ vals,
    const int*   __restrict__ row_ptr,
    const float* __restrict__ bias,
    float*       __restrict__ out, int N) {
    int t = threadIdx.x;
    int lane = t & 63;
    int g = lane >> 2;           // node group 0..15
    int l = lane & 3;            // feature slice: 8l..8l+7
    int n = (blockIdx.x * 4 + (t >> 6)) * 16 + g;
    int start = 0, end = 0;
    if (n < N) { start = row_ptr[n]; end = row_ptr[n + 1]; }

    const us8* __restrict__ y8 = (const us8*)y;   // 4 x ushort8 per row

    float a0[8], a1[8];
    #pragma unroll
    for (int i = 0; i < 8; ++i) { a0[i] = 0.f; a1[i] = 0.f; }

    for (int e = start; e < end; e += 8) {
        int ec[8];
        #pragma unroll
        for (int k = 0; k < 8; ++k) {
            int ek = e + k;
            ec[k] = (ek < end) ? ek : (end - 1);   // clamp: always in-range
        }
        int c[8];
        #pragma unroll
        for (int k = 0; k < 8; ++k) c[k] = cols[ec[k]];
        float v[8];
        #pragma unroll
        for (int k = 0; k < 8; ++k) {
            float vv = vals[ec[k]];
            v[k] = (e + k < end) ? vv : 0.0f;      // predicate via value
        }
        us8 r[8];
        #pragma unroll
        for (int k = 0; k < 8; ++k) r[k] = y8[(size_t)c[k] * 4 + l];
        #pragma unroll
        for (int k = 0; k < 8; ++k) {
            float* a = (k & 1) ? a1 : a0;          // 2 chains
            #pragma unroll
            for (int i = 0; i < 8; ++i)
                a[i] = fmaf(h2f(r[k][i]), v[k], a[i]);   // -> v_fma_mix_f32
        }
    }

    if (n < N) {
        const float* __restrict__ bp = bias + l * 8;
        f4 o0, o1;
        o0.x = fmaxf(a0[0] + a1[0] + bp[0], 0.f);
        o0.y = fmaxf(a0[1] + a1[1] + bp[1], 0.f);
        o0.z = fmaxf(a0[2] + a1[2] + bp[2], 0.f);
        o0.w = fmaxf(a0[3] + a1[3] + bp[3], 0.f);
        o1.x = fmaxf(a0[4] + a1[4] + bp[4], 0.f);
        o1.y = fmaxf(a0[5] + a1[5] + bp[5], 0.f);
        o1.z = fmaxf(a0[6] + a1[6] + bp[6], 0.f);
        o1.w = fmaxf(a0[7] + a1[7] + bp[7], 0.f);
        f4* op = (f4*)(out + (size_t)n * F + l * 8);
        __builtin_nontemporal_store(o0, op);
        __builtin_nontemporal_store(o1, op + 1);
    }
}

// ---- Fallback (ws too small): round-2 proven fp32 kernel ----
__global__ __launch_bounds__(256) void gnn_fp32_kernel(
    const float* __restrict__ x,
    const int*   __restrict__ rows,
    const int*   __restrict__ cols,
    const float* __restrict__ vals,
    const float* __restrict__ W,
    const float* __restrict__ bias,
    float*       __restrict__ out,
    int N, int E) {
    __shared__ float Wt[F * F];
    __shared__ float bS[F];
    int t = threadIdx.x;
    for (int i = t; i < F * F; i += 256)
        Wt[(i & 31) * F + (i >> 5)] = W[i];
    if (t < F) bS[t] = bias[t];
    __syncthreads();
    int lane = t & 63;
    int n = blockIdx.x * 4 + (t >> 6);
    if (n >= N) return;
    int g = lane >> 3, l = lane & 7;
    int target = n + (lane >> 5);
    int lo = 0, hi = E;
    while (lo < hi) { int mid = (lo + hi) >> 1; if (rows[mid] < target) lo = mid + 1; else hi = mid; }
    int start = __shfl(lo, 0), end = __shfl(lo, 32);
    const float4* __restrict__ x4 = (const float4*)x;
    float4 acc0 = {0,0,0,0}, acc1 = {0,0,0,0};
    for (int e0 = start; e0 < end; e0 += 16) {
        int ea = e0 + g, eb = ea + 8;
        if (ea < end) { int c = cols[ea]; float v = vals[ea]; float4 xr = x4[c * 8 + l];
            acc0.x = fmaf(xr.x, v, acc0.x); acc0.y = fmaf(xr.y, v, acc0.y);
            acc0.z = fmaf(xr.z, v, acc0.z); acc0.w = fmaf(xr.w, v, acc0.w); }
        if (eb < end) { int c = cols[eb]; float v = vals[eb]; float4 xr = x4[c * 8 + l];
            acc1.x = fmaf(xr.x, v, acc1.x); acc1.y = fmaf(xr.y, v, acc1.y);
            acc1.z = fmaf(xr.z, v, acc1.z); acc1.w = fmaf(xr.w, v, acc1.w); }
    }
    acc0.x += acc1.x; acc0.y += acc1.y; acc0.z += acc1.z; acc0.w += acc1.w;
    #pragma unroll
    for (int m = 8; m < 64; m <<= 1) {
        acc0.x += __shfl_xor(acc0.x, m); acc0.y += __shfl_xor(acc0.y, m);
        acc0.z += __shfl_xor(acc0.z, m); acc0.w += __shfl_xor(acc0.w, m);
    }
    float comp[4] = {acc0.x, acc0.y, acc0.z, acc0.w};
    int fo = lane & 31;
    float o = bS[fo];
    #pragma unroll
    for (int fi = 0; fi < F; ++fi)
        o = fmaf(__shfl(comp[fi & 3], fi >> 2), Wt[fi * F + fo], o);
    if (lane < F) out[n * F + fo] = fmaxf(o, 0.0f);
}

extern "C" void kernel_launch(void* const* d_in, const int* in_sizes, int n_in,
                              void* d_out, int out_size, void* d_ws, size_t ws_size,
                              hipStream_t stream) {
    const float* x    = (const float*)d_in[0];
    const int*   rows = (const int*)  d_in[1];
    const int*   cols = (const int*)  d_in[2];
    const float* vals = (const float*)d_in[3];
    const float* W    = (const float*)d_in[4];
    const float* bias = (const float*)d_in[5];
    float*       out  = (float*)d_out;

    int N = in_sizes[0] / F;
    int E = in_sizes[1];

    size_t rp_bytes = (size_t)(N + 1) * sizeof(int);
    size_t y_off    = (rp_bytes + 255) & ~(size_t)255;
    size_t need     = y_off + (size_t)N * F * sizeof(unsigned short);

    if (ws_size >= need) {
        int* row_ptr = (int*)d_ws;
        unsigned short* y = (unsigned short*)((char*)d_ws + y_off);
        int nxw  = (N + 63) / 64;
        int ncsr = (E + 1 + 255) / 256;
        prologue_kernel<<<nxw + ncsr, 256, 0, stream>>>(x, W, rows, y, row_ptr, N, E, nxw);
        gnn_kernel<<<(N + 63) / 64, 256, 0, stream>>>(y, cols, vals, row_ptr, bias, out, N);
    } else {
        gnn_fp32_kernel<<<(N + 3) / 4, 256, 0, stream>>>(
            x, rows, cols, vals, W, bias, out, N, E);
    }
}